// Round 13
// baseline (158.172 us; speedup 1.0000x reference)
//
#include <hip/hip_runtime.h>
#include <hip/hip_fp16.h>
#include <math.h>

#define NN 50000
#define HH 128
#define EE 600000
#define EDD 32
#define NBINS 50176   // 196*256 >= NN
#define NPRE 782      // (NN+63)/64
#define NHIST 586     // ceil(EE/1024)
#define NWG_E (EE / 64)

typedef __attribute__((ext_vector_type(8))) _Float16 half8;
typedef __attribute__((ext_vector_type(4))) float f32x4;

__device__ __forceinline__ unsigned pkh(float a, float b) {
  __half2 h = __floats2half2_rn(a, b);
  return *reinterpret_cast<unsigned*>(&h);
}
__device__ __forceinline__ unsigned hadd2u(unsigned a, unsigned b) {
  __half2 x = *reinterpret_cast<__half2*>(&a);
  __half2 y = *reinterpret_cast<__half2*>(&b);
  __half2 s = __hadd2(x, y);
  return *reinterpret_cast<unsigned*>(&s);
}
__device__ __forceinline__ unsigned hmul2u(unsigned a, unsigned b) {
  __half2 x = *reinterpret_cast<__half2*>(&a);
  __half2 y = *reinterpret_cast<__half2*>(&b);
  __half2 s = __hmul2(x, y);
  return *reinterpret_cast<unsigned*>(&s);
}
__device__ __forceinline__ short f2hs(float f) {
  __half h = __float2half_rn(f);
  return *reinterpret_cast<short*>(&h);
}
__device__ __forceinline__ float h2f(short s) {
  __half h = *reinterpret_cast<__half*>(&s);
  return __half2float(h);
}

// f32 tanh-form GELU via native v_exp_f32 / v_rcp_f32 (saturates exactly).
__device__ __forceinline__ float gelu_f(float v) {
  float u = v * fmaf(0.10294324f, v * v, 2.3022082f);
  float e = __builtin_amdgcn_exp2f(u);
  float r = __builtin_amdgcn_rcpf(e + 1.0f);
  return fmaf(-v, r, v);
}

// packed-f16 GELU (saturates exactly).
__device__ __forceinline__ __half2 gelu2(__half2 v) {
  const __half2 c2 = __floats2half2_rn(0.10294324f, 0.10294324f);
  const __half2 K2 = __floats2half2_rn(2.3022082f, 2.3022082f);
  const __half2 one2 = __floats2half2_rn(1.0f, 1.0f);
  __half2 t = __hmul2(v, v);
  __half2 p = __hfma2(t, c2, K2);
  __half2 u = __hmul2(v, p);
  __half2 e = __halves2half2(hexp2(__low2half(u)), hexp2(__high2half(u)));
  __half2 d = __hadd2(e, one2);
  __half2 r = __halves2half2(hrcp(__low2half(d)), hrcp(__high2half(d)));
  return __hfma2(__hneg2(v), r, v);
}

// ---------------------------------------------------------------------------
// k_setup (632 blocks x 256):
//   blocks 0..41 : pack eW1/nW1/nW2 f16 B-frag order (4 sub-tiles each)
//   block 42     : global dtype detect (flag=1 -> int64)
//   blocks 43,44 : W2' = eW2 @ nW1b, B-frag order, PAIR-PERMUTED K rows
//   block 45     : b2p = eb2 @ nW1b (f32)
//   blocks 46..  : dst histogram (per-block LOCAL dtype detect; chist pre-zeroed
//                  by SDMA memset)
// ---------------------------------------------------------------------------
#define FS 132
__global__ __launch_bounds__(256) void k_setup(
    const float* __restrict__ eW1, const float* __restrict__ nW1,
    const float* __restrict__ nW2, const float* __restrict__ eW2,
    const float* __restrict__ eb2, const long long* __restrict__ ei,
    long long nmax,
    short* __restrict__ pe1, short* __restrict__ pn1, short* __restrict__ pn2,
    short* __restrict__ pnW2p, float* __restrict__ b2p,
    int* __restrict__ chist, int* __restrict__ flag) {
  __shared__ short sA[64 * 136];
  __shared__ float sR[64 * FS];
  __shared__ int bad;
  const int blk = blockIdx.x;
  const int tid = threadIdx.x;

  if (blk >= 46) {                      // ---- histogram, local detect ----
    if (tid == 0) bad = 0;
    __syncthreads();
    {
      long long v = ei[tid];            // 256 samples; int32 data -> huge values
      if (v < 0 || v >= nmax) bad = 1;
    }
    __syncthreads();
    const int isL = !bad;
    int base = ((blk - 46) * 256 + tid) * 4;
    if (isL) {
      const long long* p = ei + EE;
#pragma unroll
      for (int j = 0; j < 4; ++j) {
        int e = base + j;
        if (e < EE) atomicAdd(&chist[(int)p[e]], 1);
      }
    } else {
      const int* p = (const int*)ei + EE;
      if (base + 3 < EE) {
        int4 d4 = *(const int4*)(p + base);
        atomicAdd(&chist[d4.x], 1);
        atomicAdd(&chist[d4.y], 1);
        atomicAdd(&chist[d4.z], 1);
        atomicAdd(&chist[d4.w], 1);
      } else {
        for (int j = 0; j < 4; ++j) {
          int e = base + j;
          if (e < EE) atomicAdd(&chist[p[e]], 1);
        }
      }
    }
    return;
  }
  if (blk < 42) {                       // ---- weight pack ----
    const int b = blk * 4 + (tid >> 6);
    const int l = tid & 63;
    const float* W;
    short* P;
    int bb;
    if (b < 72)       { W = eW1; P = pe1; bb = b; }
    else if (b < 136) { W = nW1; P = pn1; bb = b - 72; }
    else              { W = nW2; P = pn2; bb = b - 136; }
    const int kt = bb >> 3, ct = bb & 7;
    short v[8];
#pragma unroll
    for (int j = 0; j < 8; ++j)
      v[j] = f2hs(W[(size_t)(kt * 32 + ((l >> 4) * 8 + j)) * HH + ct * 16 + (l & 15)]);
    short* dst = P + ((size_t)bb * 64 + l) * 8;
#pragma unroll
    for (int j = 0; j < 8; ++j) dst[j] = v[j];
    return;
  }
  if (blk == 42) {                      // ---- global dtype detect ----
    if (tid == 0) bad = 0;
    __syncthreads();
    for (int i = tid; i < 2048; i += 256) {
      long long v = ei[i];
      if (v < 0 || v >= nmax) bad = 1;
    }
    __syncthreads();
    if (tid == 0) *flag = (bad ? 0 : 1);
    return;
  }
  if (blk == 45) {                      // ---- b2p ----
    if (tid < 128) {
      float acc = 0.f;
#pragma unroll 4
      for (int k = 0; k < 128; ++k)
        acc += eb2[k] * nW1[(size_t)(128 + k) * HH + tid];
      b2p[tid] = acc;
    }
    return;
  }
  // ---- W2' GEMM (blocks 43,44) ----
  {
    const int b = blk - 43;
    const int le = tid >> 2, lq = tid & 3;
    const int wv = tid >> 6, l = tid & 63, lr = l & 15, kq = l >> 4;

    half8 bf[8];
#pragma unroll
    for (int kt = 0; kt < 4; ++kt)
#pragma unroll
      for (int c = 0; c < 2; ++c) {
        half8 v;
#pragma unroll
        for (int j = 0; j < 8; ++j)
          v[j] = (_Float16)nW1[(size_t)(128 + kt * 32 + ((l >> 4) * 8 + j)) * HH +
                               (wv * 2 + c) * 16 + (l & 15)];
        bf[kt * 2 + c] = v;
      }
    {
      const float4* xs = (const float4*)(eW2 + (size_t)(64 * b + le) * HH);
#pragma unroll
      for (int i = 0; i < 4; ++i) {
        float4 a = xs[lq * 8 + i * 2], c = xs[lq * 8 + i * 2 + 1];
        uint4 u = {pkh(a.x, a.y), pkh(a.z, a.w), pkh(c.x, c.y), pkh(c.z, c.w)};
        *(uint4*)&sA[le * 136 + lq * 32 + i * 8] = u;
      }
    }
    __syncthreads();

    f32x4 acc[4][2];
    const f32x4 zero = {0.f, 0.f, 0.f, 0.f};
#pragma unroll
    for (int m = 0; m < 4; ++m) { acc[m][0] = zero; acc[m][1] = zero; }
    const short* ab = &sA[lr * 136 + kq * 8];
#pragma unroll
    for (int kt = 0; kt < 4; ++kt) {
      half8 af[4];
#pragma unroll
      for (int m = 0; m < 4; ++m) af[m] = *(const half8*)(ab + m * 16 * 136 + kt * 32);
#pragma unroll
      for (int m = 0; m < 4; ++m)
#pragma unroll
        for (int c = 0; c < 2; ++c)
          acc[m][c] = __builtin_amdgcn_mfma_f32_16x16x32_f16(af[m], bf[kt * 2 + c], acc[m][c], 0, 0, 0);
    }
#pragma unroll
    for (int c = 0; c < 2; ++c)
#pragma unroll
      for (int m = 0; m < 4; ++m)
#pragma unroll
        for (int r = 0; r < 4; ++r)
          sR[(m * 16 + kq * 4 + r) * FS + wv * 32 + c * 16 + lr] = acc[m][c][r];
    __syncthreads();

    // emit pack with pair-permuted K rows
#pragma unroll
    for (int it = 0; it < 4; ++it) {
      int item = tid + 256 * it;
      int lane = item & 63;
      int pair = item >> 6;
      int ktl = pair >> 3, ct = pair & 7;
      short v[8];
#pragma unroll
      for (int j = 0; j < 8; ++j) {
        int kpos = ktl * 32 + ((lane >> 4) * 8 + j);
        int t2 = kpos >> 1, h2 = kpos & 1;
        int rowl = (t2 >> 4) * 32 + (t2 & 15) + 16 * h2;
        int colp = ct * 16 + (lane & 15);
        v[j] = f2hs(sR[rowl * FS + colp]);
      }
      short* dst = pnW2p + (((size_t)(2 * b + ktl) * 8 + ct) * 64 + lane) * 8;
#pragma unroll
      for (int j = 0; j < 8; ++j) dst[j] = v[j];
    }
  }
}

// ---------------------------------------------------------------------------
// k_preh: blocks 0..NPRE-1: Psw = packed-pair f16 of (x@W1a + eb1),
// Pdw = packed-pair f16 of x@W1b, + zero HaggH2 rows.
// blocks NPRE..NPRE+195: scan1 (exclusive-in-block prefix of chist + bsum).
// ---------------------------------------------------------------------------
__global__ __launch_bounds__(256, 4) void k_preh(
    const float* __restrict__ x, const short* __restrict__ pW1,
    const float* __restrict__ eb1,
    unsigned* __restrict__ Psw, unsigned* __restrict__ Pdw,
    unsigned* __restrict__ HaggH2,
    const int* __restrict__ chist, int* __restrict__ tmp, int* __restrict__ bsum) {
  __shared__ short sX[64 * 136];
  __shared__ int buf[2][256];
  const int blk = blockIdx.x;
  const int tid = threadIdx.x;

  if (blk >= NPRE) {                    // ---- scan1 ----
    int sb = blk - NPRE;
    int i = sb * 256 + tid;
    int self = chist[i];
    buf[0][tid] = self;
    __syncthreads();
    int cur = 0;
    for (int o = 1; o < 256; o <<= 1) {
      int v = buf[cur][tid];
      if (tid >= o) v += buf[cur][tid - o];
      buf[cur ^ 1][tid] = v;
      __syncthreads();
      cur ^= 1;
    }
    tmp[i] = buf[cur][tid] - self;
    if (tid == 255) bsum[sb] = buf[cur][255];
    return;
  }

  const int r0 = blk * 64;
  const int le = tid >> 2, lq = tid & 3;
  const int wv = tid >> 6, l = tid & 63, lr = l & 15, kq = l >> 4;

  // zero this block's HaggH2 rows
  {
    int gr = r0 + le;
    if (gr < NN) {
      uint4 z = {0, 0, 0, 0};
      uint4* hp = (uint4*)(HaggH2 + (size_t)gr * 64);
#pragma unroll
      for (int i = 0; i < 4; ++i) hp[lq * 4 + i] = z;
    }
  }

  const float b1c0 = eb1[wv * 32 + lr];
  const float b1c1 = eb1[wv * 32 + 16 + lr];

  const half8* bp = (const half8*)pW1;
  half8 fa[8], fb[8];
#pragma unroll
  for (int kt = 0; kt < 4; ++kt)
#pragma unroll
    for (int c = 0; c < 2; ++c) {
      fa[kt * 2 + c] = bp[(kt * 8 + wv * 2 + c) * 64 + l];
      fb[kt * 2 + c] = bp[((kt + 4) * 8 + wv * 2 + c) * 64 + l];
    }
  {
    int gr = r0 + le;
    if (gr < NN) {
      const float4* xs = (const float4*)(x + (size_t)gr * HH);
#pragma unroll
      for (int i = 0; i < 4; ++i) {
        float4 a = xs[lq * 8 + i * 2], c = xs[lq * 8 + i * 2 + 1];
        uint4 u = {pkh(a.x, a.y), pkh(a.z, a.w), pkh(c.x, c.y), pkh(c.z, c.w)};
        *(uint4*)&sX[le * 136 + lq * 32 + i * 8] = u;
      }
    } else {
      uint4 z = {0, 0, 0, 0};
#pragma unroll
      for (int i = 0; i < 4; ++i) *(uint4*)&sX[le * 136 + lq * 32 + i * 8] = z;
    }
  }
  __syncthreads();

  f32x4 as_[4][2], ad[4][2];
  const f32x4 zero = {0.f, 0.f, 0.f, 0.f};
#pragma unroll
  for (int m = 0; m < 4; ++m) { as_[m][0] = zero; as_[m][1] = zero; ad[m][0] = zero; ad[m][1] = zero; }
  const short* ab = &sX[lr * 136 + kq * 8];
#pragma unroll
  for (int kt = 0; kt < 4; ++kt) {
    half8 af[4];
#pragma unroll
    for (int m = 0; m < 4; ++m) af[m] = *(const half8*)(ab + m * 16 * 136 + kt * 32);
#pragma unroll
    for (int m = 0; m < 4; ++m)
#pragma unroll
      for (int c = 0; c < 2; ++c) {
        as_[m][c] = __builtin_amdgcn_mfma_f32_16x16x32_f16(af[m], fa[kt * 2 + c], as_[m][c], 0, 0, 0);
        ad[m][c] = __builtin_amdgcn_mfma_f32_16x16x32_f16(af[m], fb[kt * 2 + c], ad[m][c], 0, 0, 0);
      }
  }
#pragma unroll
  for (int m = 0; m < 4; ++m)
#pragma unroll
    for (int r = 0; r < 4; ++r) {
      int grow = r0 + m * 16 + kq * 4 + r;
      if (grow < NN) {
        Psw[(size_t)grow * 64 + wv * 16 + lr] =
            pkh(as_[m][0][r] + b1c0, as_[m][1][r] + b1c1);
        Pdw[(size_t)grow * 64 + wv * 16 + lr] = pkh(ad[m][0][r], ad[m][1][r]);
      }
    }
}

// ---------------------------------------------------------------------------
// k_scatter: per-block re-scan of bsum, then scatter edges into dst-sorted
// u64 records: src | dst<<20 | eid<<40.
// ---------------------------------------------------------------------------
__global__ void k_scatter(const void* __restrict__ eiv, const int* __restrict__ flag,
                          const int* __restrict__ tmp,
                          const int* __restrict__ bsum, int* __restrict__ cntW,
                          unsigned long long* __restrict__ e8) {
  __shared__ int sB[2][256];
  const int t = threadIdx.x;
  int orig = (t < 196) ? bsum[t] : 0;
  sB[0][t] = orig;
  __syncthreads();
  int cur = 0;
  for (int o = 1; o < 256; o <<= 1) {
    int v = sB[cur][t];
    if (t >= o) v += sB[cur][t - o];
    sB[cur ^ 1][t] = v;
    __syncthreads();
    cur ^= 1;
  }
  sB[1][t] = sB[0][t] - orig;
  __syncthreads();

  int e = blockIdx.x * 256 + t;
  if (e >= EE) return;
  int s, d;
  if (*flag) {
    const long long* p = (const long long*)eiv;
    s = (int)p[e];
    d = (int)p[EE + e];
  } else {
    const int* p = (const int*)eiv;
    s = p[e];
    d = p[EE + e];
  }
  int base = tmp[d] + sB[1][d >> 8];
  int pos = base + atomicAdd(&cntW[d], 1);
  e8[pos] = (unsigned long long)s | ((unsigned long long)d << 20) |
            ((unsigned long long)e << 40);
}

// ---------------------------------------------------------------------------
// k_edge: h = gelu(Ps[src](+b1) + Pd[dst] + ea@W1c); segment-sum h (packed
// f16) -> one pk_add_f16 atomic per segment into HaggH2[dst].
// XOR-swizzled LDS (20480B -> 8 blocks/CU); dst boundaries via shfl/ballot.
// ---------------------------------------------------------------------------
__global__ __launch_bounds__(256, 8) void k_edge(
    const unsigned* __restrict__ Psw, const unsigned* __restrict__ Pdw,
    const float* __restrict__ ea,
    const short* __restrict__ pW1,
    const unsigned long long* __restrict__ e8, unsigned* __restrict__ HaggH2) {
  // sFp: 64 rows x 16 uint4, XOR-swizzled: u4slot = u4col ^ (row & 15)
  // sEA: 64 rows x 4 uint4,  XOR-swizzled: u4slot = u4col ^ (row & 3)
  __shared__ uint4 sFp4[64 * 16];   // 16384 B
  __shared__ uint4 sEA4[64 * 4];    //  4096 B

  // bijective XCD-chunked swizzle
  int orig = blockIdx.x;
  const int q8 = NWG_E >> 3, r8 = NWG_E & 7;
  int xcd = orig & 7, lid = orig >> 3;
  int swz = (xcd < r8) ? xcd * (q8 + 1) + lid
                       : r8 * (q8 + 1) + (xcd - r8) * q8 + lid;

  const int tid = threadIdx.x;
  const int e0 = swz * 64;
  const int le = tid >> 2, lq = tid & 3;
  const int wv = tid >> 6, l = tid & 63, lr = l & 15, kq = l >> 4;

  // W1c (kt=8 of packed eW1) -> registers
  half8 w1c[2];
#pragma unroll
  for (int c = 0; c < 2; ++c)
    w1c[c] = ((const half8*)pW1)[(64 + wv * 2 + c) * 64 + l];

  const unsigned long long er = e8[e0 + le];
  const int gs = (int)(er & 0xFFFFF);
  const int gd = (int)((er >> 20) & 0xFFFFF);
  const int ge = (int)(er >> 40);

  // ---- stage: packed P-sum pairs [row][pairU4^row] + ea ----
  {
    const uint4* ps = (const uint4*)(Psw + (size_t)gs * 64);
    const uint4* pd = (const uint4*)(Pdw + (size_t)gd * 64);
#pragma unroll
    for (int i = 0; i < 4; ++i) {
      uint4 a = ps[lq * 4 + i];
      uint4 b = pd[lq * 4 + i];
      uint4 s = {hadd2u(a.x, b.x), hadd2u(a.y, b.y), hadd2u(a.z, b.z), hadd2u(a.w, b.w)};
      sFp4[le * 16 + ((lq * 4 + i) ^ (le & 15))] = s;
    }
    const float4* ep = (const float4*)(ea + (size_t)ge * EDD);
    float4 a = ep[lq * 2], b = ep[lq * 2 + 1];
    uint4 u = {pkh(a.x, a.y), pkh(a.z, a.w), pkh(b.x, b.y), pkh(b.z, b.w)};
    sEA4[le * 4 + (lq ^ (le & 3))] = u;
  }
  __syncthreads();

  // ---- ea @ W1c : single K=32 tile, 8 MFMA ----
  f32x4 acc[4][2];
  const f32x4 zero = {0.f, 0.f, 0.f, 0.f};
#pragma unroll
  for (int m = 0; m < 4; ++m) { acc[m][0] = zero; acc[m][1] = zero; }
  {
#pragma unroll
    for (int m = 0; m < 4; ++m) {
      uint4 av = sEA4[(m * 16 + lr) * 4 + (kq ^ (lr & 3))];
      half8 af = *reinterpret_cast<half8*>(&av);
#pragma unroll
      for (int c = 0; c < 2; ++c)
        acc[m][c] = __builtin_amdgcn_mfma_f32_16x16x32_f16(af, w1c[c], acc[m][c], 0, 0, 0);
    }
  }

  // ---- h = gelu2(pk(acc) + P) -> regs (packed pairs) ----
  const unsigned* sFpW = (const unsigned*)sFp4;
  const int pairU4 = wv * 4 + (lr >> 2);
  const int pairW = lr & 3;
  unsigned pr[4][4];
#pragma unroll
  for (int m = 0; m < 4; ++m)
#pragma unroll
    for (int r = 0; r < 4; ++r) {
      const int row = m * 16 + kq * 4 + r;
      unsigned up = sFpW[(row * 16 + (pairU4 ^ (row & 15))) * 4 + pairW];
      __half2 P = *reinterpret_cast<__half2*>(&up);
      __half2 v = __hadd2(__floats2half2_rn(acc[m][0][r], acc[m][1][r]), P);
      __half2 hg = gelu2(v);
      pr[m][r] = *reinterpret_cast<unsigned*>(&hg);
    }
  __syncthreads();   // all reads of sFp done before transposed overwrite

  // ---- transposed write: sFp_T[pair][rowU4 ^ pair&15] ----
  {
    const int pair = wv * 16 + lr;
#pragma unroll
    for (int m = 0; m < 4; ++m) {
      uint4 u = {pr[m][0], pr[m][1], pr[m][2], pr[m][3]};
      sFp4[pair * 16 + ((m * 4 + kq) ^ lr)] = u;
    }
  }
  __syncthreads();

  // ---- segmented sum over sorted dst runs; boundaries via shfl/ballot ----
  {
    const int p = tid & 63;           // pair (lane within wave)
    const int q = tid >> 6;           // wave = 16-row strip
    // lane 4*jj of wave q holds gd for row q*16+jj
    int gnxt = __shfl_down(gd, 4, 64);
    unsigned long long bmask = __ballot(gd != gnxt);
    __half2 run = __floats2half2_rn(0.f, 0.f);
#pragma unroll
    for (int i = 0; i < 4; ++i) {
      uint4 u4 = sFp4[p * 16 + ((q * 4 + i) ^ (p & 15))];
      unsigned uu[4] = {u4.x, u4.y, u4.z, u4.w};
#pragma unroll
      for (int j = 0; j < 4; ++j) {
        const int jj = i * 4 + j;
        run = __hadd2(run, *reinterpret_cast<__half2*>(&uu[j]));
        int dcur = __shfl(gd, jj * 4, 64);
        bool last = (jj == 15) || ((bmask >> (jj * 4)) & 1);
        if (last) {
          unsafeAtomicAdd((__half2*)&HaggH2[(size_t)dcur * 64 + p], run);
          run = __floats2half2_rn(0.f, 0.f);
        }
      }
    }
  }
}

// ---------------------------------------------------------------------------
// k_node: hidden = gelu(x@nW1a + Hm@W2' + nb1 + f*b2p); out = LN(hidden@nW2
// + nb2 + x). Hm staged from packed HaggH2 (pair layout, pk_mul by rinv);
// W2' rows pre-permuted. Hidden GELU -> cols 128..255; x f16 reused for
// residual.
// ---------------------------------------------------------------------------
#define NS 264
__global__ __launch_bounds__(256, 4) void k_node(
    const float* __restrict__ x,
    const unsigned* __restrict__ HaggH2, const int* __restrict__ chist,
    const short* __restrict__ pn1, const short* __restrict__ pnW2p,
    const float* __restrict__ nb1, const float* __restrict__ b2p,
    const short* __restrict__ pn2, const float* __restrict__ nb2,
    const float* __restrict__ g, const float* __restrict__ be,
    float* __restrict__ out) {
  __shared__ short sA[64 * NS];
  __shared__ float sP[64 * 4];
  __shared__ float sP2[64 * 4];
  __shared__ float sFac[64];

  const int tid = threadIdx.x;
  const int r0 = blockIdx.x * 64;
  const int le = tid >> 2;
  const int lq = tid & 3;
  const int wv = tid >> 6;
  const int l = tid & 63;
  const int lr = l & 15;
  const int kq = l >> 4;

  const half8* bpa = (const half8*)pn1;
  const half8* bpc = (const half8*)pnW2p;
  half8 b1f[16];
#pragma unroll
  for (int kt = 0; kt < 4; ++kt)
#pragma unroll
    for (int c = 0; c < 2; ++c) {
      b1f[kt * 2 + c] = bpa[(kt * 8 + wv * 2 + c) * 64 + l];
      b1f[(kt + 4) * 2 + c] = bpc[(kt * 8 + wv * 2 + c) * 64 + l];
    }

  {
    const int gr = r0 + le;
    short* row = &sA[le * NS];
    if (gr < NN) {
      float cntf = (float)chist[gr];
      float rinv = 1.0f / (cntf + 1e-8f);
      if (lq == 0) sFac[le] = cntf * rinv;
      const float4* xs = (const float4*)(x + (size_t)gr * HH);
#pragma unroll
      for (int i = 0; i < 4; ++i) {
        float4 a = xs[lq * 8 + i * 2], c = xs[lq * 8 + i * 2 + 1];
        uint4 u = {pkh(a.x, a.y), pkh(a.z, a.w), pkh(c.x, c.y), pkh(c.z, c.w)};
        *(uint4*)(row + lq * 32 + i * 8) = u;
      }
      const unsigned rv2 = pkh(rinv, rinv);
      const uint4* hs = (const uint4*)(HaggH2 + (size_t)gr * 64);
#pragma unroll
      for (int i = 0; i < 4; ++i) {
        uint4 u = hs[lq * 4 + i];
        u.x = hmul2u(u.x, rv2);
        u.y = hmul2u(u.y, rv2);
        u.z = hmul2u(u.z, rv2);
        u.w = hmul2u(u.w, rv2);
        *(uint4*)(row + 128 + lq * 32 + i * 8) = u;
      }
    } else {
      if (lq == 0) sFac[le] = 0.f;
      uint4 z = {0, 0, 0, 0};
#pragma unroll
      for (int i = 0; i < 8; ++i) *(uint4*)(row + lq * 64 + i * 8) = z;
    }
  }
  __syncthreads();

  f32x4 acc[4][2];
  const f32x4 zero = {0.f, 0.f, 0.f, 0.f};
#pragma unroll
  for (int m = 0; m < 4; ++m) { acc[m][0] = zero; acc[m][1] = zero; }
  const short* ab = &sA[lr * NS + kq * 8];
#pragma unroll
  for (int kt = 0; kt < 8; ++kt) {
    half8 af[4];
#pragma unroll
    for (int m = 0; m < 4; ++m)
      af[m] = *(const half8*)(ab + m * 16 * NS + kt * 32);
#pragma unroll
    for (int m = 0; m < 4; ++m)
#pragma unroll
      for (int c = 0; c < 2; ++c)
        acc[m][c] = __builtin_amdgcn_mfma_f32_16x16x32_f16(af[m], b1f[kt * 2 + c], acc[m][c], 0, 0, 0);
  }

  const half8* bp2 = (const half8*)pn2;
  half8 b2f_[8];
#pragma unroll
  for (int kt = 0; kt < 4; ++kt)
#pragma unroll
    for (int c = 0; c < 2; ++c)
      b2f_[kt * 2 + c] = bp2[(kt * 8 + wv * 2 + c) * 64 + l];

  __syncthreads();

  // ---- bias (nb1 + f*b2p) + GELU -> sA cols 128..255 ----
#pragma unroll
  for (int c = 0; c < 2; ++c) {
    const int col = wv * 32 + c * 16 + lr;
    const float b1v = nb1[col];
    const float b2pv = b2p[col];
#pragma unroll
    for (int m = 0; m < 4; ++m)
#pragma unroll
      for (int r = 0; r < 4; ++r) {
        const int row = m * 16 + kq * 4 + r;
        float fac = sFac[row];
        sA[row * NS + 128 + col] = f2hs(gelu_f(acc[m][c][r] + b1v + fac * b2pv));
      }
  }
  __syncthreads();

  f32x4 acc2[4][2];
#pragma unroll
  for (int m = 0; m < 4; ++m) { acc2[m][0] = zero; acc2[m][1] = zero; }
#pragma unroll
  for (int kt = 0; kt < 4; ++kt) {
    half8 af[4];
#pragma unroll
    for (int m = 0; m < 4; ++m)
      af[m] = *(const half8*)(ab + m * 16 * NS + 128 + kt * 32);
#pragma unroll
    for (int m = 0; m < 4; ++m)
#pragma unroll
      for (int c = 0; c < 2; ++c)
        acc2[m][c] = __builtin_amdgcn_mfma_f32_16x16x32_f16(af[m], b2f_[kt * 2 + c], acc2[m][c], 0, 0, 0);
  }

  // ---- + b2 + residual (x f16 from LDS cols 0..127) ----
  float val[4][2][4];
#pragma unroll
  for (int c = 0; c < 2; ++c) {
    const int col = wv * 32 + c * 16 + lr;
    const float b2v = nb2[col];
#pragma unroll
    for (int m = 0; m < 4; ++m)
#pragma unroll
      for (int r = 0; r < 4; ++r) {
        const int lrow = m * 16 + kq * 4 + r;
        float xr = h2f(sA[lrow * NS + col]);
        val[m][c][r] = acc2[m][c][r] + b2v + xr;
      }
  }
#pragma unroll
  for (int m = 0; m < 4; ++m)
#pragma unroll
    for (int r = 0; r < 4; ++r) {
      float s = val[m][0][r] + val[m][1][r];
      float s2 = val[m][0][r] * val[m][0][r] + val[m][1][r] * val[m][1][r];
#pragma unroll
      for (int o = 1; o < 16; o <<= 1) {
        s += __shfl_xor(s, o);
        s2 += __shfl_xor(s2, o);
      }
      if (lr == 0) {
        const int row = m * 16 + kq * 4 + r;
        sP[row * 4 + wv] = s;
        sP2[row * 4 + wv] = s2;
      }
    }
  __syncthreads();

#pragma unroll
  for (int c = 0; c < 2; ++c) {
    const int col = wv * 32 + c * 16 + lr;
    const float gv = g[col];
    const float bv = be[col];
#pragma unroll
    for (int m = 0; m < 4; ++m)
#pragma unroll
      for (int r = 0; r < 4; ++r) {
        const int lrow = m * 16 + kq * 4 + r;
        const int row = r0 + lrow;
        if (row < NN) {
          float4 ps = *(float4*)&sP[lrow * 4];
          float4 qs = *(float4*)&sP2[lrow * 4];
          float s = ps.x + ps.y + ps.z + ps.w;
          float s2 = qs.x + qs.y + qs.z + qs.w;
          float mu = s * 0.0078125f;
          float var = s2 * 0.0078125f - mu * mu;
          float rs = rsqrtf(var + 1e-5f);
          out[(size_t)row * HH + col] = (val[m][c][r] - mu) * rs * gv + bv;
        }
      }
  }
}

extern "C" void kernel_launch(void* const* d_in, const int* in_sizes, int n_in,
                              void* d_out, int out_size, void* d_ws, size_t ws_size,
                              hipStream_t stream) {
  const float* x = (const float*)d_in[0];
  const void* ei = d_in[1];
  const float* ea = (const float*)d_in[2];
  const float* eW1 = (const float*)d_in[3];
  const float* eb1 = (const float*)d_in[4];
  const float* eW2 = (const float*)d_in[5];
  const float* eb2 = (const float*)d_in[6];
  const float* nW1 = (const float*)d_in[7];
  const float* nb1 = (const float*)d_in[8];
  const float* nW2 = (const float*)d_in[9];
  const float* nb2 = (const float*)d_in[10];
  const float* lng = (const float*)d_in[11];
  const float* lnb = (const float*)d_in[12];
  float* out = (float*)d_out;

  char* w = (char*)d_ws;
  size_t off = 0;
  auto alloc = [&](size_t bytes) { void* p = w + off; off = (off + bytes + 255) & ~(size_t)255; return p; };
  unsigned* HaggH2 = (unsigned*)alloc((size_t)NN * 64 * 4);  // packed half2, zeroed by k_preh
  int* chist = (int*)alloc((size_t)NBINS * 4);               // zeroed by memset
  int* cntW = (int*)alloc((size_t)NBINS * 4);                // zeroed by memset (contiguous)
  short* pe1 = (short*)alloc((size_t)72 * 512 * 2);
  short* pn1 = (short*)alloc((size_t)64 * 512 * 2);
  short* pn2 = (short*)alloc((size_t)32 * 512 * 2);
  short* pnW2p = (short*)alloc((size_t)32 * 512 * 2);
  float* b2p = (float*)alloc(HH * 4);
  unsigned long long* e8 = (unsigned long long*)alloc((size_t)EE * 8);
  int* tmpS = (int*)alloc((size_t)NBINS * 4);
  int* bsum = (int*)alloc(256 * 4);
  int* flag = (int*)alloc(256);
  unsigned* Psw = (unsigned*)alloc((size_t)NN * 64 * 4);
  unsigned* Pdw = (unsigned*)alloc((size_t)NN * 64 * 4);

  // small SDMA memset: chist + cntW only (400 KB)
  hipMemsetAsync(chist, 0, (size_t)NBINS * 4 * 2, stream);
  k_setup<<<46 + NHIST, 256, 0, stream>>>(eW1, nW1, nW2, eW2, eb2,
                                          (const long long*)ei, (long long)NN,
                                          pe1, pn1, pn2, pnW2p, b2p, chist, flag);
  k_preh<<<NPRE + 196, 256, 0, stream>>>(x, pe1, eb1, Psw, Pdw, HaggH2, chist, tmpS, bsum);
  k_scatter<<<(EE + 255) / 256, 256, 0, stream>>>(ei, flag, tmpS, bsum, cntW, e8);
  k_edge<<<NWG_E, 256, 0, stream>>>(Psw, Pdw, ea, pe1, e8, HaggH2);
  k_node<<<(NN + 63) / 64, 256, 0, stream>>>(x, HaggH2, chist, pn1, pnW2p, nb1, b2p, pn2, nb2, lng, lnb, out);
}

// Round 14
// 152.665 us; speedup vs baseline: 1.0361x; 1.0361x over previous
//
#include <hip/hip_runtime.h>
#include <hip/hip_fp16.h>
#include <math.h>

#define NN 50000
#define HH 128
#define EE 600000
#define EDD 32
#define NBINS 50176   // 196*256 >= NN
#define NPRE 782      // (NN+63)/64
#define NHIST 586     // ceil(EE/1024)
#define NWG_E (EE / 64)

typedef __attribute__((ext_vector_type(8))) _Float16 half8;
typedef __attribute__((ext_vector_type(4))) float f32x4;

__device__ __forceinline__ unsigned pkh(float a, float b) {
  __half2 h = __floats2half2_rn(a, b);
  return *reinterpret_cast<unsigned*>(&h);
}
__device__ __forceinline__ unsigned hadd2u(unsigned a, unsigned b) {
  __half2 x = *reinterpret_cast<__half2*>(&a);
  __half2 y = *reinterpret_cast<__half2*>(&b);
  __half2 s = __hadd2(x, y);
  return *reinterpret_cast<unsigned*>(&s);
}
__device__ __forceinline__ unsigned hmul2u(unsigned a, unsigned b) {
  __half2 x = *reinterpret_cast<__half2*>(&a);
  __half2 y = *reinterpret_cast<__half2*>(&b);
  __half2 s = __hmul2(x, y);
  return *reinterpret_cast<unsigned*>(&s);
}
__device__ __forceinline__ short f2hs(float f) {
  __half h = __float2half_rn(f);
  return *reinterpret_cast<short*>(&h);
}
__device__ __forceinline__ float h2f(short s) {
  __half h = *reinterpret_cast<__half*>(&s);
  return __half2float(h);
}

// f32 tanh-form GELU via native v_exp_f32 / v_rcp_f32 (saturates exactly).
__device__ __forceinline__ float gelu_f(float v) {
  float u = v * fmaf(0.10294324f, v * v, 2.3022082f);
  float e = __builtin_amdgcn_exp2f(u);
  float r = __builtin_amdgcn_rcpf(e + 1.0f);
  return fmaf(-v, r, v);
}

// packed-f16 GELU (saturates exactly).
__device__ __forceinline__ __half2 gelu2(__half2 v) {
  const __half2 c2 = __floats2half2_rn(0.10294324f, 0.10294324f);
  const __half2 K2 = __floats2half2_rn(2.3022082f, 2.3022082f);
  const __half2 one2 = __floats2half2_rn(1.0f, 1.0f);
  __half2 t = __hmul2(v, v);
  __half2 p = __hfma2(t, c2, K2);
  __half2 u = __hmul2(v, p);
  __half2 e = __halves2half2(hexp2(__low2half(u)), hexp2(__high2half(u)));
  __half2 d = __hadd2(e, one2);
  __half2 r = __halves2half2(hrcp(__low2half(d)), hrcp(__high2half(d)));
  return __hfma2(__hneg2(v), r, v);
}

// ---------------------------------------------------------------------------
// k_setup (95 blocks x 256):
//   blocks 0..41 : pack eW1/nW1/nW2 f16 B-frag order (4 sub-tiles each)
//   block 42     : detect int64 vs int32 edge_index (flag=1 -> int64)
//   blocks 43..91: zero chist+cntW (2*NBINS ints)
//   blocks 92,93 : W2' = eW2 @ nW1b, B-frag order with PAIR-PERMUTED K rows
//   block 94     : b2p = eb2 @ nW1b (f32)
// ---------------------------------------------------------------------------
#define FS 132
__global__ __launch_bounds__(256) void k_setup(
    const float* __restrict__ eW1, const float* __restrict__ nW1,
    const float* __restrict__ nW2, const float* __restrict__ eW2,
    const float* __restrict__ eb2, const long long* __restrict__ ei,
    long long nmax,
    short* __restrict__ pe1, short* __restrict__ pn1, short* __restrict__ pn2,
    short* __restrict__ pnW2p, float* __restrict__ b2p,
    int* __restrict__ zbase, int* __restrict__ flag) {
  __shared__ short sA[64 * 136];
  __shared__ float sR[64 * FS];
  __shared__ int bad;
  const int blk = blockIdx.x;
  const int tid = threadIdx.x;

  if (blk < 42) {                       // ---- weight pack ----
    const int b = blk * 4 + (tid >> 6);
    const int l = tid & 63;
    const float* W;
    short* P;
    int bb;
    if (b < 72)       { W = eW1; P = pe1; bb = b; }
    else if (b < 136) { W = nW1; P = pn1; bb = b - 72; }
    else              { W = nW2; P = pn2; bb = b - 136; }
    const int kt = bb >> 3, ct = bb & 7;
    short v[8];
#pragma unroll
    for (int j = 0; j < 8; ++j)
      v[j] = f2hs(W[(size_t)(kt * 32 + ((l >> 4) * 8 + j)) * HH + ct * 16 + (l & 15)]);
    short* dst = P + ((size_t)bb * 64 + l) * 8;
#pragma unroll
    for (int j = 0; j < 8; ++j) dst[j] = v[j];
    return;
  }
  if (blk == 42) {                      // ---- dtype detect ----
    if (tid == 0) bad = 0;
    __syncthreads();
    for (int i = tid; i < 2048; i += 256) {
      long long v = ei[i];
      if (v < 0 || v >= nmax) bad = 1;
    }
    __syncthreads();
    if (tid == 0) *flag = (bad ? 0 : 1);
    return;
  }
  if (blk < 92) {                       // ---- zero chist+cntW ----
    int idx = (blk - 43) * 2048 + tid * 8;
    int4 z = {0, 0, 0, 0};
    *(int4*)(zbase + idx) = z;
    *(int4*)(zbase + idx + 4) = z;
    return;
  }
  if (blk == 94) {                      // ---- b2p ----
    if (tid < 128) {
      float acc = 0.f;
#pragma unroll 4
      for (int k = 0; k < 128; ++k)
        acc += eb2[k] * nW1[(size_t)(128 + k) * HH + tid];
      b2p[tid] = acc;
    }
    return;
  }
  // ---- W2' GEMM (blocks 92,93) ----
  {
    const int b = blk - 92;
    const int le = tid >> 2, lq = tid & 3;
    const int wv = tid >> 6, l = tid & 63, lr = l & 15, kq = l >> 4;

    half8 bf[8];
#pragma unroll
    for (int kt = 0; kt < 4; ++kt)
#pragma unroll
      for (int c = 0; c < 2; ++c) {
        half8 v;
#pragma unroll
        for (int j = 0; j < 8; ++j)
          v[j] = (_Float16)nW1[(size_t)(128 + kt * 32 + ((l >> 4) * 8 + j)) * HH +
                               (wv * 2 + c) * 16 + (l & 15)];
        bf[kt * 2 + c] = v;
      }
    {
      const float4* xs = (const float4*)(eW2 + (size_t)(64 * b + le) * HH);
#pragma unroll
      for (int i = 0; i < 4; ++i) {
        float4 a = xs[lq * 8 + i * 2], c = xs[lq * 8 + i * 2 + 1];
        uint4 u = {pkh(a.x, a.y), pkh(a.z, a.w), pkh(c.x, c.y), pkh(c.z, c.w)};
        *(uint4*)&sA[le * 136 + lq * 32 + i * 8] = u;
      }
    }
    __syncthreads();

    f32x4 acc[4][2];
    const f32x4 zero = {0.f, 0.f, 0.f, 0.f};
#pragma unroll
    for (int m = 0; m < 4; ++m) { acc[m][0] = zero; acc[m][1] = zero; }
    const short* ab = &sA[lr * 136 + kq * 8];
#pragma unroll
    for (int kt = 0; kt < 4; ++kt) {
      half8 af[4];
#pragma unroll
      for (int m = 0; m < 4; ++m) af[m] = *(const half8*)(ab + m * 16 * 136 + kt * 32);
#pragma unroll
      for (int m = 0; m < 4; ++m)
#pragma unroll
        for (int c = 0; c < 2; ++c)
          acc[m][c] = __builtin_amdgcn_mfma_f32_16x16x32_f16(af[m], bf[kt * 2 + c], acc[m][c], 0, 0, 0);
    }
#pragma unroll
    for (int c = 0; c < 2; ++c)
#pragma unroll
      for (int m = 0; m < 4; ++m)
#pragma unroll
        for (int r = 0; r < 4; ++r)
          sR[(m * 16 + kq * 4 + r) * FS + wv * 32 + c * 16 + lr] = acc[m][c][r];
    __syncthreads();

    // emit pack with pair-permuted K rows:
    //   kpos = ktl*32 + (lane>>4)*8 + j; t = kpos>>1; h = kpos&1;
    //   row_local = (t>>4)*32 + (t&15) + 16h
#pragma unroll
    for (int it = 0; it < 4; ++it) {
      int item = tid + 256 * it;
      int lane = item & 63;
      int pair = item >> 6;      // 0..15
      int ktl = pair >> 3, ct = pair & 7;
      short v[8];
#pragma unroll
      for (int j = 0; j < 8; ++j) {
        int kpos = ktl * 32 + ((lane >> 4) * 8 + j);
        int t2 = kpos >> 1, h2 = kpos & 1;
        int rowl = (t2 >> 4) * 32 + (t2 & 15) + 16 * h2;
        int colp = ct * 16 + (lane & 15);
        v[j] = f2hs(sR[rowl * FS + colp]);
      }
      short* dst = pnW2p + (((size_t)(2 * b + ktl) * 8 + ct) * 64 + lane) * 8;
#pragma unroll
      for (int j = 0; j < 8; ++j) dst[j] = v[j];
    }
  }
}

// ---------------------------------------------------------------------------
// k_preh: blocks 0..NPRE-1: Psw = packed-pair f16 of (x@W1a + eb1),
// Pdw = packed-pair f16 of x@W1b, + zero HaggH2 rows.
// blocks NPRE..: vectorized dst histogram.
// ---------------------------------------------------------------------------
__global__ __launch_bounds__(256, 4) void k_preh(
    const float* __restrict__ x, const short* __restrict__ pW1,
    const float* __restrict__ eb1,
    const void* __restrict__ eiv, const int* __restrict__ flag,
    unsigned* __restrict__ Psw, unsigned* __restrict__ Pdw,
    unsigned* __restrict__ HaggH2, int* __restrict__ chist) {
  __shared__ short sX[64 * 136];
  const int blk = blockIdx.x;
  const int tid = threadIdx.x;

  if (blk >= NPRE) {                    // ---- histogram (4 edges/thread) ----
    int base = ((blk - NPRE) * 256 + tid) * 4;
    if (*flag) {
      const long long* p = (const long long*)eiv + EE;
#pragma unroll
      for (int j = 0; j < 4; ++j) {
        int e = base + j;
        if (e < EE) atomicAdd(&chist[(int)p[e]], 1);
      }
    } else {
      const int* p = (const int*)eiv + EE;
      if (base + 3 < EE) {
        int4 d4 = *(const int4*)(p + base);
        atomicAdd(&chist[d4.x], 1);
        atomicAdd(&chist[d4.y], 1);
        atomicAdd(&chist[d4.z], 1);
        atomicAdd(&chist[d4.w], 1);
      } else {
        for (int j = 0; j < 4; ++j) {
          int e = base + j;
          if (e < EE) atomicAdd(&chist[p[e]], 1);
        }
      }
    }
    return;
  }

  const int r0 = blk * 64;
  const int le = tid >> 2, lq = tid & 3;
  const int wv = tid >> 6, l = tid & 63, lr = l & 15, kq = l >> 4;

  // zero this block's HaggH2 rows (overlaps with staging/MFMA)
  {
    int gr = r0 + le;
    if (gr < NN) {
      uint4 z = {0, 0, 0, 0};
      uint4* hp = (uint4*)(HaggH2 + (size_t)gr * 64);
#pragma unroll
      for (int i = 0; i < 4; ++i) hp[lq * 4 + i] = z;
    }
  }

  const float b1c0 = eb1[wv * 32 + lr];
  const float b1c1 = eb1[wv * 32 + 16 + lr];

  const half8* bp = (const half8*)pW1;
  half8 fa[8], fb[8];
#pragma unroll
  for (int kt = 0; kt < 4; ++kt)
#pragma unroll
    for (int c = 0; c < 2; ++c) {
      fa[kt * 2 + c] = bp[(kt * 8 + wv * 2 + c) * 64 + l];
      fb[kt * 2 + c] = bp[((kt + 4) * 8 + wv * 2 + c) * 64 + l];
    }
  {
    int gr = r0 + le;
    if (gr < NN) {
      const float4* xs = (const float4*)(x + (size_t)gr * HH);
#pragma unroll
      for (int i = 0; i < 4; ++i) {
        float4 a = xs[lq * 8 + i * 2], c = xs[lq * 8 + i * 2 + 1];
        uint4 u = {pkh(a.x, a.y), pkh(a.z, a.w), pkh(c.x, c.y), pkh(c.z, c.w)};
        *(uint4*)&sX[le * 136 + lq * 32 + i * 8] = u;
      }
    } else {
      uint4 z = {0, 0, 0, 0};
#pragma unroll
      for (int i = 0; i < 4; ++i) *(uint4*)&sX[le * 136 + lq * 32 + i * 8] = z;
    }
  }
  __syncthreads();

  f32x4 as_[4][2], ad[4][2];
  const f32x4 zero = {0.f, 0.f, 0.f, 0.f};
#pragma unroll
  for (int m = 0; m < 4; ++m) { as_[m][0] = zero; as_[m][1] = zero; ad[m][0] = zero; ad[m][1] = zero; }
  const short* ab = &sX[lr * 136 + kq * 8];
#pragma unroll
  for (int kt = 0; kt < 4; ++kt) {
    half8 af[4];
#pragma unroll
    for (int m = 0; m < 4; ++m) af[m] = *(const half8*)(ab + m * 16 * 136 + kt * 32);
#pragma unroll
    for (int m = 0; m < 4; ++m)
#pragma unroll
      for (int c = 0; c < 2; ++c) {
        as_[m][c] = __builtin_amdgcn_mfma_f32_16x16x32_f16(af[m], fa[kt * 2 + c], as_[m][c], 0, 0, 0);
        ad[m][c] = __builtin_amdgcn_mfma_f32_16x16x32_f16(af[m], fb[kt * 2 + c], ad[m][c], 0, 0, 0);
      }
  }
#pragma unroll
  for (int m = 0; m < 4; ++m)
#pragma unroll
    for (int r = 0; r < 4; ++r) {
      int grow = r0 + m * 16 + kq * 4 + r;
      if (grow < NN) {
        Psw[(size_t)grow * 64 + wv * 16 + lr] =
            pkh(as_[m][0][r] + b1c0, as_[m][1][r] + b1c1);
        Pdw[(size_t)grow * 64 + wv * 16 + lr] = pkh(ad[m][0][r], ad[m][1][r]);
      }
    }
}

// ---------------------------------------------------------------------------
// prefix scan: EXCLUSIVE within block (tmp) + block sums.
// ---------------------------------------------------------------------------
__global__ void k_scan1(const int* __restrict__ chist, int* __restrict__ tmp,
                        int* __restrict__ bsum) {
  __shared__ int buf[2][256];
  int t = threadIdx.x;
  int i = blockIdx.x * 256 + t;
  int self = chist[i];
  buf[0][t] = self;
  __syncthreads();
  int cur = 0;
  for (int o = 1; o < 256; o <<= 1) {
    int v = buf[cur][t];
    if (t >= o) v += buf[cur][t - o];
    buf[cur ^ 1][t] = v;
    __syncthreads();
    cur ^= 1;
  }
  tmp[i] = buf[cur][t] - self;      // exclusive within block
  if (t == 255) bsum[blockIdx.x] = buf[cur][255];
}

// ---------------------------------------------------------------------------
// k_scatter: per-block re-scan of bsum, then scatter edges into dst-sorted
// u64 records: src | dst<<20 | eid<<40.
// ---------------------------------------------------------------------------
__global__ void k_scatter(const void* __restrict__ eiv, const int* __restrict__ flag,
                          const int* __restrict__ tmp,
                          const int* __restrict__ bsum, int* __restrict__ cntW,
                          unsigned long long* __restrict__ e8) {
  __shared__ int sB[2][256];
  const int t = threadIdx.x;
  int orig = (t < 196) ? bsum[t] : 0;
  sB[0][t] = orig;
  __syncthreads();
  int cur = 0;
  for (int o = 1; o < 256; o <<= 1) {
    int v = sB[cur][t];
    if (t >= o) v += sB[cur][t - o];
    sB[cur ^ 1][t] = v;
    __syncthreads();
    cur ^= 1;
  }
  sB[1][t] = sB[0][t] - orig;
  __syncthreads();

  int e = blockIdx.x * 256 + t;
  if (e >= EE) return;
  int s, d;
  if (*flag) {
    const long long* p = (const long long*)eiv;
    s = (int)p[e];
    d = (int)p[EE + e];
  } else {
    const int* p = (const int*)eiv;
    s = p[e];
    d = p[EE + e];
  }
  int base = tmp[d] + sB[1][d >> 8];
  int pos = base + atomicAdd(&cntW[d], 1);
  e8[pos] = (unsigned long long)s | ((unsigned long long)d << 20) |
            ((unsigned long long)e << 40);
}

// ---------------------------------------------------------------------------
// k_edge: h = gelu(Ps[src](+b1) + Pd[dst] + ea@W1c); segment-sum h (packed
// f16) -> one pk_add_f16 atomic per segment into HaggH2[dst].
// XOR-swizzled LDS (20480B -> 8 blocks/CU); dst boundaries via shfl/ballot.
// ---------------------------------------------------------------------------
__global__ __launch_bounds__(256, 8) void k_edge(
    const unsigned* __restrict__ Psw, const unsigned* __restrict__ Pdw,
    const float* __restrict__ ea,
    const short* __restrict__ pW1,
    const unsigned long long* __restrict__ e8, unsigned* __restrict__ HaggH2) {
  // sFp: 64 rows x 16 uint4, XOR-swizzled: u4slot = u4col ^ (row & 15)
  // sEA: 64 rows x 4 uint4,  XOR-swizzled: u4slot = u4col ^ (row & 3)
  __shared__ uint4 sFp4[64 * 16];   // 16384 B
  __shared__ uint4 sEA4[64 * 4];    //  4096 B

  // bijective XCD-chunked swizzle
  int orig = blockIdx.x;
  const int q8 = NWG_E >> 3, r8 = NWG_E & 7;
  int xcd = orig & 7, lid = orig >> 3;
  int swz = (xcd < r8) ? xcd * (q8 + 1) + lid
                       : r8 * (q8 + 1) + (xcd - r8) * q8 + lid;

  const int tid = threadIdx.x;
  const int e0 = swz * 64;
  const int le = tid >> 2, lq = tid & 3;
  const int wv = tid >> 6, l = tid & 63, lr = l & 15, kq = l >> 4;

  // W1c (kt=8 of packed eW1) -> registers
  half8 w1c[2];
#pragma unroll
  for (int c = 0; c < 2; ++c)
    w1c[c] = ((const half8*)pW1)[(64 + wv * 2 + c) * 64 + l];

  const unsigned long long er = e8[e0 + le];
  const int gs = (int)(er & 0xFFFFF);
  const int gd = (int)((er >> 20) & 0xFFFFF);
  const int ge = (int)(er >> 40);

  // ---- stage: packed P-sum pairs [row][pairU4^row] + ea ----
  {
    const uint4* ps = (const uint4*)(Psw + (size_t)gs * 64);
    const uint4* pd = (const uint4*)(Pdw + (size_t)gd * 64);
#pragma unroll
    for (int i = 0; i < 4; ++i) {
      uint4 a = ps[lq * 4 + i];
      uint4 b = pd[lq * 4 + i];
      uint4 s = {hadd2u(a.x, b.x), hadd2u(a.y, b.y), hadd2u(a.z, b.z), hadd2u(a.w, b.w)};
      sFp4[le * 16 + ((lq * 4 + i) ^ (le & 15))] = s;
    }
    const float4* ep = (const float4*)(ea + (size_t)ge * EDD);
    float4 a = ep[lq * 2], b = ep[lq * 2 + 1];
    uint4 u = {pkh(a.x, a.y), pkh(a.z, a.w), pkh(b.x, b.y), pkh(b.z, b.w)};
    sEA4[le * 4 + (lq ^ (le & 3))] = u;
  }
  __syncthreads();

  // ---- ea @ W1c : single K=32 tile, 8 MFMA ----
  f32x4 acc[4][2];
  const f32x4 zero = {0.f, 0.f, 0.f, 0.f};
#pragma unroll
  for (int m = 0; m < 4; ++m) { acc[m][0] = zero; acc[m][1] = zero; }
  {
#pragma unroll
    for (int m = 0; m < 4; ++m) {
      uint4 av = sEA4[(m * 16 + lr) * 4 + (kq ^ (lr & 3))];
      half8 af = *reinterpret_cast<half8*>(&av);
#pragma unroll
      for (int c = 0; c < 2; ++c)
        acc[m][c] = __builtin_amdgcn_mfma_f32_16x16x32_f16(af, w1c[c], acc[m][c], 0, 0, 0);
    }
  }

  // ---- h = gelu2(pk(acc) + P) -> regs (packed pairs) ----
  const unsigned* sFpW = (const unsigned*)sFp4;
  const int pairU4 = wv * 4 + (lr >> 2);
  const int pairW = lr & 3;
  unsigned pr[4][4];
#pragma unroll
  for (int m = 0; m < 4; ++m)
#pragma unroll
    for (int r = 0; r < 4; ++r) {
      const int row = m * 16 + kq * 4 + r;
      unsigned up = sFpW[(row * 16 + (pairU4 ^ (row & 15))) * 4 + pairW];
      __half2 P = *reinterpret_cast<__half2*>(&up);
      __half2 v = __hadd2(__floats2half2_rn(acc[m][0][r], acc[m][1][r]), P);
      __half2 hg = gelu2(v);
      pr[m][r] = *reinterpret_cast<unsigned*>(&hg);
    }
  __syncthreads();   // all reads of sFp done before transposed overwrite

  // ---- transposed write: sFp_T[pair][rowU4 ^ pair&15] ----
  {
    const int pair = wv * 16 + lr;
#pragma unroll
    for (int m = 0; m < 4; ++m) {
      uint4 u = {pr[m][0], pr[m][1], pr[m][2], pr[m][3]};
      sFp4[pair * 16 + ((m * 4 + kq) ^ lr)] = u;
    }
  }
  __syncthreads();

  // ---- segmented sum over sorted dst runs; boundaries via shfl/ballot ----
  {
    const int p = tid & 63;           // pair (lane within wave)
    const int q = tid >> 6;           // wave = 16-row strip
    // lane 4*jj of wave q holds gd for row q*16+jj
    int gnxt = __shfl_down(gd, 4, 64);
    unsigned long long bmask = __ballot(gd != gnxt);
    __half2 run = __floats2half2_rn(0.f, 0.f);
#pragma unroll
    for (int i = 0; i < 4; ++i) {
      uint4 u4 = sFp4[p * 16 + ((q * 4 + i) ^ (p & 15))];
      unsigned uu[4] = {u4.x, u4.y, u4.z, u4.w};
#pragma unroll
      for (int j = 0; j < 4; ++j) {
        const int jj = i * 4 + j;
        run = __hadd2(run, *reinterpret_cast<__half2*>(&uu[j]));
        int dcur = __shfl(gd, jj * 4, 64);
        bool last = (jj == 15) || ((bmask >> (jj * 4)) & 1);
        if (last) {
          unsafeAtomicAdd((__half2*)&HaggH2[(size_t)dcur * 64 + p], run);
          run = __floats2half2_rn(0.f, 0.f);
        }
      }
    }
  }
}

// ---------------------------------------------------------------------------
// k_node: hidden = gelu(x@nW1a + Hm@W2' + nb1 + f*b2p); out = LN(hidden@nW2
// + nb2 + x). Hm staged from packed HaggH2 (pair layout, pk_mul by rinv);
// W2' rows pre-permuted. Hidden GELU -> cols 128..255; x f16 reused for
// residual.
// ---------------------------------------------------------------------------
#define NS 264
__global__ __launch_bounds__(256, 4) void k_node(
    const float* __restrict__ x,
    const unsigned* __restrict__ HaggH2, const int* __restrict__ chist,
    const short* __restrict__ pn1, const short* __restrict__ pnW2p,
    const float* __restrict__ nb1, const float* __restrict__ b2p,
    const short* __restrict__ pn2, const float* __restrict__ nb2,
    const float* __restrict__ g, const float* __restrict__ be,
    float* __restrict__ out) {
  __shared__ short sA[64 * NS];
  __shared__ float sP[64 * 4];
  __shared__ float sP2[64 * 4];
  __shared__ float sFac[64];

  const int tid = threadIdx.x;
  const int r0 = blockIdx.x * 64;
  const int le = tid >> 2;
  const int lq = tid & 3;
  const int wv = tid >> 6;
  const int l = tid & 63;
  const int lr = l & 15;
  const int kq = l >> 4;

  const half8* bpa = (const half8*)pn1;
  const half8* bpc = (const half8*)pnW2p;
  half8 b1f[16];
#pragma unroll
  for (int kt = 0; kt < 4; ++kt)
#pragma unroll
    for (int c = 0; c < 2; ++c) {
      b1f[kt * 2 + c] = bpa[(kt * 8 + wv * 2 + c) * 64 + l];
      b1f[(kt + 4) * 2 + c] = bpc[(kt * 8 + wv * 2 + c) * 64 + l];
    }

  {
    const int gr = r0 + le;
    short* row = &sA[le * NS];
    if (gr < NN) {
      float cntf = (float)chist[gr];
      float rinv = 1.0f / (cntf + 1e-8f);
      if (lq == 0) sFac[le] = cntf * rinv;
      const float4* xs = (const float4*)(x + (size_t)gr * HH);
#pragma unroll
      for (int i = 0; i < 4; ++i) {
        float4 a = xs[lq * 8 + i * 2], c = xs[lq * 8 + i * 2 + 1];
        uint4 u = {pkh(a.x, a.y), pkh(a.z, a.w), pkh(c.x, c.y), pkh(c.z, c.w)};
        *(uint4*)(row + lq * 32 + i * 8) = u;
      }
      const unsigned rv2 = pkh(rinv, rinv);
      const uint4* hs = (const uint4*)(HaggH2 + (size_t)gr * 64);
#pragma unroll
      for (int i = 0; i < 4; ++i) {
        uint4 u = hs[lq * 4 + i];
        u.x = hmul2u(u.x, rv2);
        u.y = hmul2u(u.y, rv2);
        u.z = hmul2u(u.z, rv2);
        u.w = hmul2u(u.w, rv2);
        *(uint4*)(row + 128 + lq * 32 + i * 8) = u;
      }
    } else {
      if (lq == 0) sFac[le] = 0.f;
      uint4 z = {0, 0, 0, 0};
#pragma unroll
      for (int i = 0; i < 8; ++i) *(uint4*)(row + lq * 64 + i * 8) = z;
    }
  }
  __syncthreads();

  f32x4 acc[4][2];
  const f32x4 zero = {0.f, 0.f, 0.f, 0.f};
#pragma unroll
  for (int m = 0; m < 4; ++m) { acc[m][0] = zero; acc[m][1] = zero; }
  const short* ab = &sA[lr * NS + kq * 8];
#pragma unroll
  for (int kt = 0; kt < 8; ++kt) {
    half8 af[4];
#pragma unroll
    for (int m = 0; m < 4; ++m)
      af[m] = *(const half8*)(ab + m * 16 * NS + kt * 32);
#pragma unroll
    for (int m = 0; m < 4; ++m)
#pragma unroll
      for (int c = 0; c < 2; ++c)
        acc[m][c] = __builtin_amdgcn_mfma_f32_16x16x32_f16(af[m], b1f[kt * 2 + c], acc[m][c], 0, 0, 0);
  }

  const half8* bp2 = (const half8*)pn2;
  half8 b2f_[8];
#pragma unroll
  for (int kt = 0; kt < 4; ++kt)
#pragma unroll
    for (int c = 0; c < 2; ++c)
      b2f_[kt * 2 + c] = bp2[(kt * 8 + wv * 2 + c) * 64 + l];

  __syncthreads();

  // ---- bias (nb1 + f*b2p) + GELU -> sA cols 128..255 ----
#pragma unroll
  for (int c = 0; c < 2; ++c) {
    const int col = wv * 32 + c * 16 + lr;
    const float b1v = nb1[col];
    const float b2pv = b2p[col];
#pragma unroll
    for (int m = 0; m < 4; ++m)
#pragma unroll
      for (int r = 0; r < 4; ++r) {
        const int row = m * 16 + kq * 4 + r;
        float fac = sFac[row];
        sA[row * NS + 128 + col] = f2hs(gelu_f(acc[m][c][r] + b1v + fac * b2pv));
      }
  }
  __syncthreads();

  f32x4 acc2[4][2];
#pragma unroll
  for (int m = 0; m < 4; ++m) { acc2[m][0] = zero; acc2[m][1] = zero; }
#pragma unroll
  for (int kt = 0; kt < 4; ++kt) {
    half8 af[4];
#pragma unroll
    for (int m = 0; m < 4; ++m)
      af[m] = *(const half8*)(ab + m * 16 * NS + 128 + kt * 32);
#pragma unroll
    for (int m = 0; m < 4; ++m)
#pragma unroll
      for (int c = 0; c < 2; ++c)
        acc2[m][c] = __builtin_amdgcn_mfma_f32_16x16x32_f16(af[m], b2f_[kt * 2 + c], acc2[m][c], 0, 0, 0);
  }

  // ---- + b2 + residual (x f16 from LDS cols 0..127) ----
  float val[4][2][4];
#pragma unroll
  for (int c = 0; c < 2; ++c) {
    const int col = wv * 32 + c * 16 + lr;
    const float b2v = nb2[col];
#pragma unroll
    for (int m = 0; m < 4; ++m)
#pragma unroll
      for (int r = 0; r < 4; ++r) {
        const int lrow = m * 16 + kq * 4 + r;
        float xr = h2f(sA[lrow * NS + col]);
        val[m][c][r] = acc2[m][c][r] + b2v + xr;
      }
  }
#pragma unroll
  for (int m = 0; m < 4; ++m)
#pragma unroll
    for (int r = 0; r < 4; ++r) {
      float s = val[m][0][r] + val[m][1][r];
      float s2 = val[m][0][r] * val[m][0][r] + val[m][1][r] * val[m][1][r];
#pragma unroll
      for (int o = 1; o < 16; o <<= 1) {
        s += __shfl_xor(s, o);
        s2 += __shfl_xor(s2, o);
      }
      if (lr == 0) {
        const int row = m * 16 + kq * 4 + r;
        sP[row * 4 + wv] = s;
        sP2[row * 4 + wv] = s2;
      }
    }
  __syncthreads();

#pragma unroll
  for (int c = 0; c < 2; ++c) {
    const int col = wv * 32 + c * 16 + lr;
    const float gv = g[col];
    const float bv = be[col];
#pragma unroll
    for (int m = 0; m < 4; ++m)
#pragma unroll
      for (int r = 0; r < 4; ++r) {
        const int lrow = m * 16 + kq * 4 + r;
        const int row = r0 + lrow;
        if (row < NN) {
          float4 ps = *(float4*)&sP[lrow * 4];
          float4 qs = *(float4*)&sP2[lrow * 4];
          float s = ps.x + ps.y + ps.z + ps.w;
          float s2 = qs.x + qs.y + qs.z + qs.w;
          float mu = s * 0.0078125f;
          float var = s2 * 0.0078125f - mu * mu;
          float rs = rsqrtf(var + 1e-5f);
          out[(size_t)row * HH + col] = (val[m][c][r] - mu) * rs * gv + bv;
        }
      }
  }
}

extern "C" void kernel_launch(void* const* d_in, const int* in_sizes, int n_in,
                              void* d_out, int out_size, void* d_ws, size_t ws_size,
                              hipStream_t stream) {
  const float* x = (const float*)d_in[0];
  const void* ei = d_in[1];
  const float* ea = (const float*)d_in[2];
  const float* eW1 = (const float*)d_in[3];
  const float* eb1 = (const float*)d_in[4];
  const float* eW2 = (const float*)d_in[5];
  const float* eb2 = (const float*)d_in[6];
  const float* nW1 = (const float*)d_in[7];
  const float* nb1 = (const float*)d_in[8];
  const float* nW2 = (const float*)d_in[9];
  const float* nb2 = (const float*)d_in[10];
  const float* lng = (const float*)d_in[11];
  const float* lnb = (const float*)d_in[12];
  float* out = (float*)d_out;

  char* w = (char*)d_ws;
  size_t off = 0;
  auto alloc = [&](size_t bytes) { void* p = w + off; off = (off + bytes + 255) & ~(size_t)255; return p; };
  unsigned* HaggH2 = (unsigned*)alloc((size_t)NN * 64 * 4);  // packed half2, zeroed by k_preh
  int* chist = (int*)alloc((size_t)NBINS * 4);               // zeroed by k_setup
  int* cntW = (int*)alloc((size_t)NBINS * 4);                // zeroed by k_setup (contiguous)
  short* pe1 = (short*)alloc((size_t)72 * 512 * 2);
  short* pn1 = (short*)alloc((size_t)64 * 512 * 2);
  short* pn2 = (short*)alloc((size_t)32 * 512 * 2);
  short* pnW2p = (short*)alloc((size_t)32 * 512 * 2);
  float* b2p = (float*)alloc(HH * 4);
  unsigned long long* e8 = (unsigned long long*)alloc((size_t)EE * 8);
  int* tmpS = (int*)alloc((size_t)NBINS * 4);
  int* bsum = (int*)alloc(256 * 4);
  int* flag = (int*)alloc(256);
  unsigned* Psw = (unsigned*)alloc((size_t)NN * 64 * 4);
  unsigned* Pdw = (unsigned*)alloc((size_t)NN * 64 * 4);

  k_setup<<<95, 256, 0, stream>>>(eW1, nW1, nW2, eW2, eb2, (const long long*)ei,
                                  (long long)NN, pe1, pn1, pn2, pnW2p, b2p, chist, flag);
  k_preh<<<NPRE + NHIST, 256, 0, stream>>>(x, pe1, eb1, ei, flag, Psw, Pdw, HaggH2, chist);
  k_scan1<<<NBINS / 256, 256, 0, stream>>>(chist, tmpS, bsum);
  k_scatter<<<(EE + 255) / 256, 256, 0, stream>>>(ei, flag, tmpS, bsum, cntW, e8);
  k_edge<<<NWG_E, 256, 0, stream>>>(Psw, Pdw, ea, pe1, e8, HaggH2);
  k_node<<<(NN + 63) / 64, 256, 0, stream>>>(x, HaggH2, chist, pn1, pnW2p, nb1, b2p, pn2, nb2, lng, lnb, out);
}